// Round 1
// baseline (866.684 us; speedup 1.0000x reference)
//
#include <hip/hip_runtime.h>
#include <hip/hip_bf16.h>
#include <cstdint>
#include <cmath>

typedef __bf16 bf16;
typedef __attribute__((ext_vector_type(8))) __bf16 bf16x8;
typedef __attribute__((ext_vector_type(4))) __bf16 bf16x4;
typedef __attribute__((ext_vector_type(4))) float f32x4;

#define T_SEQ   2048
#define D_MODEL 4096
#define KV_DIM  1024
#define NH      32
#define NKV     8
#define HD      128

// ---------------- fp32 -> bf16 convert (vectorized) ----------------
__global__ void cvt_f32_bf16(const float* __restrict__ in, bf16* __restrict__ out, int n) {
    int i = (blockIdx.x * 256 + threadIdx.x) * 4;
    if (i >= n) return;
    float4 v = *(const float4*)(in + i);
    bf16x4 o = { (bf16)v.x, (bf16)v.y, (bf16)v.z, (bf16)v.w };
    *(bf16x4*)(out + i) = o;
}

// -------- fp32 [R][C] -> bf16 [C][R] transpose (LDS 32x33 tile) --------
__global__ void trans_f32_bf16(const float* __restrict__ in, bf16* __restrict__ out, int R, int C) {
    __shared__ float tile[32][33];
    int tc = C >> 5;
    int br = blockIdx.x / tc, bc = blockIdx.x % tc;
    int r0 = br << 5, c0 = bc << 5;
    int lr = threadIdx.x >> 5, lc = threadIdx.x & 31;
#pragma unroll
    for (int i = 0; i < 4; ++i)
        tile[lr + i * 8][lc] = in[(size_t)(r0 + lr + i * 8) * C + c0 + lc];
    __syncthreads();
#pragma unroll
    for (int i = 0; i < 4; ++i) {
        int oc = lr + i * 8;
        out[(size_t)(c0 + oc) * R + r0 + lc] = (bf16)tile[lc][oc];
    }
}

// -------- bf16 [R][C] -> bf16 [C][R] transpose --------
__global__ void trans_bf16(const bf16* __restrict__ in, bf16* __restrict__ out, int R, int C) {
    __shared__ bf16 tile[32][33];
    int tc = C >> 5;
    int br = blockIdx.x / tc, bc = blockIdx.x % tc;
    int r0 = br << 5, c0 = bc << 5;
    int lr = threadIdx.x >> 5, lc = threadIdx.x & 31;
#pragma unroll
    for (int i = 0; i < 4; ++i)
        tile[lr + i * 8][lc] = in[(size_t)(r0 + lr + i * 8) * C + c0 + lc];
    __syncthreads();
#pragma unroll
    for (int i = 0; i < 4; ++i) {
        int oc = lr + i * 8;
        out[(size_t)(c0 + oc) * R + r0 + lc] = tile[lc][oc];
    }
}

// ---------------- RoPE tables ----------------
__global__ void rope_table(float* __restrict__ cosT, float* __restrict__ sinT) {
    int i = blockIdx.x * 256 + threadIdx.x;  // T_SEQ*64
    if (i >= T_SEQ * 64) return;
    int t = i >> 6, j = i & 63;
    float inv = powf(10000.0f, -(float)j / 64.0f);
    float ang = (float)t * inv;
    cosT[i] = cosf(ang);
    sinT[i] = sinf(ang);
}

// ---------------- RoPE apply, in place on bf16 [T][H*128] ----------------
__global__ void rope_apply(bf16* __restrict__ qk, const float* __restrict__ cosT,
                           const float* __restrict__ sinT, int H, int stride) {
    int i = blockIdx.x * 256 + threadIdx.x;  // T*H*64
    if (i >= T_SEQ * H * 64) return;
    int j = i & 63;
    int h = (i >> 6) % H;
    int t = i / (64 * H);
    size_t base = (size_t)t * stride + h * HD;
    float a = (float)qk[base + j];
    float b = (float)qk[base + j + 64];
    float c = cosT[t * 64 + j], s = sinT[t * 64 + j];
    qk[base + j]      = (bf16)(a * c - b * s);
    qk[base + j + 64] = (bf16)(b * c + a * s);
}

// ---------------- GEMM: C[M][N] = A[M][K] * Bt[N][K]^T  (bf16, fp32 accum) ----------------
// 128x128 tile, BK=64, 4 waves each computing 64x64 (4x4 fragments of 16x16x32 MFMA)
template <bool F32OUT>
__global__ __launch_bounds__(256, 3) void gemm_nt_128(const bf16* __restrict__ A,
                                                      const bf16* __restrict__ Bt,
                                                      void* __restrict__ Cout,
                                                      int M, int N, int K) {
    __shared__ bf16 ldsA[128 * 72];  // padded row stride 72 elems (144 B)
    __shared__ bf16 ldsB[128 * 72];
    const int tiles_n = N >> 7;
    const int bm = blockIdx.x / tiles_n;
    const int bn = blockIdx.x % tiles_n;
    const int tid = threadIdx.x;
    const int lane = tid & 63;
    const int wid = tid >> 6;
    const int wr = wid >> 1, wc = wid & 1;
    const int l16 = lane & 15, l4 = lane >> 4;
    f32x4 acc[4][4] = {};
    const size_t row0 = (size_t)bm * 128, col0 = (size_t)bn * 128;
    const bf16* Abase = A + row0 * K;
    const bf16* Bbase = Bt + col0 * K;

    for (int k0 = 0; k0 < K; k0 += 64) {
#pragma unroll
        for (int c = 0; c < 4; ++c) {
            int idx = c * 256 + tid;
            int r = idx >> 3;
            int col = (idx & 7) * 8;
            bf16x8 va = *(const bf16x8*)(Abase + (size_t)r * K + k0 + col);
            bf16x8 vb = *(const bf16x8*)(Bbase + (size_t)r * K + k0 + col);
            *(bf16x8*)&ldsA[r * 72 + col] = va;
            *(bf16x8*)&ldsB[r * 72 + col] = vb;
        }
        __syncthreads();
#pragma unroll
        for (int kk = 0; kk < 2; ++kk) {
            bf16x8 af[4], bfr[4];
#pragma unroll
            for (int m = 0; m < 4; ++m)
                af[m] = *(const bf16x8*)&ldsA[(wr * 64 + m * 16 + l16) * 72 + kk * 32 + l4 * 8];
#pragma unroll
            for (int n = 0; n < 4; ++n)
                bfr[n] = *(const bf16x8*)&ldsB[(wc * 64 + n * 16 + l16) * 72 + kk * 32 + l4 * 8];
#pragma unroll
            for (int m = 0; m < 4; ++m)
#pragma unroll
                for (int n = 0; n < 4; ++n)
                    acc[m][n] = __builtin_amdgcn_mfma_f32_16x16x32_bf16(af[m], bfr[n], acc[m][n], 0, 0, 0);
        }
        __syncthreads();
    }
#pragma unroll
    for (int m = 0; m < 4; ++m)
#pragma unroll
        for (int n = 0; n < 4; ++n)
#pragma unroll
            for (int r = 0; r < 4; ++r) {
                size_t row = row0 + wr * 64 + m * 16 + l4 * 4 + r;
                size_t col = col0 + wc * 64 + n * 16 + l16;
                float v = acc[m][n][r];
                if (F32OUT)
                    ((float*)Cout)[row * N + col] = v;
                else
                    ((bf16*)Cout)[row * N + col] = (bf16)v;
            }
}

// ---------------- causal GQA flash attention ----------------
// 1 wave per (head, 16 q rows); K-tiles of 32 keys; online softmax.
__global__ __launch_bounds__(256, 4) void flash_attn(const bf16* __restrict__ Q,
                                                     const bf16* __restrict__ Kb,
                                                     const bf16* __restrict__ Vt,
                                                     bf16* __restrict__ ctx) {
    __shared__ bf16 P_lds[4][16 * 40];  // per-wave P tile, padded stride 40
    const int tid = threadIdx.x, lane = tid & 63, wid = tid >> 6;
    const int l16 = lane & 15, l4 = lane >> 4;
    int task = blockIdx.x + 1024 * wid;   // 4096 wave-tasks
    int h = task & 31;
    int q0 = (task >> 5) * 16;
    int hk = h >> 2;
    const bf16* qb = Q + (size_t)q0 * D_MODEL + h * HD;
    bf16x8 qf[4];
#pragma unroll
    for (int kk = 0; kk < 4; ++kk)
        qf[kk] = *(const bf16x8*)(qb + (size_t)l16 * D_MODEL + kk * 32 + l4 * 8);
    f32x4 acc[8] = {};
    float m_r[4], l_r[4];
#pragma unroll
    for (int r = 0; r < 4; ++r) { m_r[r] = -INFINITY; l_r[r] = 0.f; }
    const float scale = 0.08838834764831845f;  // 1/sqrt(128)
    const int qend = q0 + 15;
    bf16* Pw = P_lds[wid];

    for (int k0 = 0; k0 <= qend; k0 += 32) {
        f32x4 s[2] = {};
#pragma unroll
        for (int n = 0; n < 2; ++n)
#pragma unroll
            for (int kk = 0; kk < 4; ++kk) {
                const bf16* kp = Kb + (size_t)(k0 + n * 16 + l16) * KV_DIM + hk * HD + kk * 32 + l4 * 8;
                bf16x8 kf = *(const bf16x8*)kp;
                s[n] = __builtin_amdgcn_mfma_f32_16x16x32_bf16(qf[kk], kf, s[n], 0, 0, 0);
            }
        // scale + causal mask
#pragma unroll
        for (int n = 0; n < 2; ++n)
#pragma unroll
            for (int r = 0; r < 4; ++r) {
                int key = k0 + n * 16 + l16;
                int row = q0 + l4 * 4 + r;
                float sv = s[n][r] * scale;
                s[n][r] = (key > row) ? -INFINITY : sv;
            }
        // online softmax
        float f[4], mn[4];
#pragma unroll
        for (int r = 0; r < 4; ++r) {
            float v = fmaxf(s[0][r], s[1][r]);
            v = fmaxf(v, __shfl_xor(v, 1));
            v = fmaxf(v, __shfl_xor(v, 2));
            v = fmaxf(v, __shfl_xor(v, 4));
            v = fmaxf(v, __shfl_xor(v, 8));
            mn[r] = fmaxf(m_r[r], v);
            f[r] = __expf(m_r[r] - mn[r]);
            m_r[r] = mn[r];
        }
#pragma unroll
        for (int n = 0; n < 2; ++n)
#pragma unroll
            for (int r = 0; r < 4; ++r)
                s[n][r] = __expf(s[n][r] - mn[r]);  // exp(-inf)=0 for masked
#pragma unroll
        for (int r = 0; r < 4; ++r) {
            float ps = s[0][r] + s[1][r];
            ps += __shfl_xor(ps, 1);
            ps += __shfl_xor(ps, 2);
            ps += __shfl_xor(ps, 4);
            ps += __shfl_xor(ps, 8);
            l_r[r] = l_r[r] * f[r] + ps;
        }
#pragma unroll
        for (int n = 0; n < 8; ++n)
#pragma unroll
            for (int r = 0; r < 4; ++r)
                acc[n][r] *= f[r];
        // P -> LDS (bf16), then PV
#pragma unroll
        for (int n = 0; n < 2; ++n)
#pragma unroll
            for (int r = 0; r < 4; ++r)
                Pw[(l4 * 4 + r) * 40 + n * 16 + l16] = (bf16)s[n][r];
        bf16x8 pf = *(const bf16x8*)&Pw[l16 * 40 + l4 * 8];  // same-wave DS ordering
#pragma unroll
        for (int n = 0; n < 8; ++n) {
            const bf16* vp = Vt + (size_t)(hk * 128 + n * 16 + l16) * T_SEQ + k0 + l4 * 8;
            bf16x8 vf = *(const bf16x8*)vp;
            acc[n] = __builtin_amdgcn_mfma_f32_16x16x32_bf16(pf, vf, acc[n], 0, 0, 0);
        }
    }
#pragma unroll
    for (int n = 0; n < 8; ++n)
#pragma unroll
        for (int r = 0; r < 4; ++r) {
            int row = q0 + l4 * 4 + r;
            ctx[(size_t)row * D_MODEL + h * HD + n * 16 + l16] = (bf16)(acc[n][r] / l_r[r]);
        }
}

// ---------------- host ----------------
extern "C" void kernel_launch(void* const* d_in, const int* in_sizes, int n_in,
                              void* d_out, int out_size, void* d_ws, size_t ws_size,
                              hipStream_t stream) {
    const float* x  = (const float*)d_in[0];
    const float* wq = (const float*)d_in[1];
    const float* wk = (const float*)d_in[2];
    const float* wv = (const float*)d_in[3];
    const float* wo = (const float*)d_in[4];
    float* out = (float*)d_out;

    char* ws = (char*)d_ws;
    size_t off = 0;
    auto alloc = [&](size_t bytes) {
        void* p = ws + off;
        off += (bytes + 255) & ~(size_t)255;
        return p;
    };
    bf16* xb   = (bf16*)alloc((size_t)T_SEQ * D_MODEL * 2);
    bf16* wqt  = (bf16*)alloc((size_t)D_MODEL * D_MODEL * 2);
    bf16* wkt  = (bf16*)alloc((size_t)KV_DIM * D_MODEL * 2);
    bf16* wvt  = (bf16*)alloc((size_t)KV_DIM * D_MODEL * 2);
    bf16* wot  = (bf16*)alloc((size_t)D_MODEL * D_MODEL * 2);
    bf16* q    = (bf16*)alloc((size_t)T_SEQ * D_MODEL * 2);
    bf16* k    = (bf16*)alloc((size_t)T_SEQ * KV_DIM * 2);
    bf16* v    = (bf16*)alloc((size_t)T_SEQ * KV_DIM * 2);
    bf16* vt   = (bf16*)alloc((size_t)KV_DIM * T_SEQ * 2);
    bf16* ctx  = (bf16*)alloc((size_t)T_SEQ * D_MODEL * 2);
    float* cosT = (float*)alloc((size_t)T_SEQ * 64 * 4);
    float* sinT = (float*)alloc((size_t)T_SEQ * 64 * 4);

    // conversions / transposes
    cvt_f32_bf16<<<(T_SEQ * D_MODEL) / 1024, 256, 0, stream>>>(x, xb, T_SEQ * D_MODEL);
    trans_f32_bf16<<<(D_MODEL / 32) * (D_MODEL / 32), 256, 0, stream>>>(wq, wqt, D_MODEL, D_MODEL);
    trans_f32_bf16<<<(D_MODEL / 32) * (KV_DIM / 32), 256, 0, stream>>>(wk, wkt, D_MODEL, KV_DIM);
    trans_f32_bf16<<<(D_MODEL / 32) * (KV_DIM / 32), 256, 0, stream>>>(wv, wvt, D_MODEL, KV_DIM);
    trans_f32_bf16<<<(D_MODEL / 32) * (D_MODEL / 32), 256, 0, stream>>>(wo, wot, D_MODEL, D_MODEL);
    rope_table<<<(T_SEQ * 64) / 256, 256, 0, stream>>>(cosT, sinT);

    // projections
    gemm_nt_128<false><<<(T_SEQ / 128) * (D_MODEL / 128), 256, 0, stream>>>(xb, wqt, q, T_SEQ, D_MODEL, D_MODEL);
    gemm_nt_128<false><<<(T_SEQ / 128) * (KV_DIM / 128), 256, 0, stream>>>(xb, wkt, k, T_SEQ, KV_DIM, D_MODEL);
    gemm_nt_128<false><<<(T_SEQ / 128) * (KV_DIM / 128), 256, 0, stream>>>(xb, wvt, v, T_SEQ, KV_DIM, D_MODEL);

    // RoPE
    rope_apply<<<(T_SEQ * NH * 64) / 256, 256, 0, stream>>>(q, cosT, sinT, NH, D_MODEL);
    rope_apply<<<(T_SEQ * NKV * 64) / 256, 256, 0, stream>>>(k, cosT, sinT, NKV, KV_DIM);

    // V^T per kv-head: [2048][1024] -> [1024][2048]
    trans_bf16<<<(T_SEQ / 32) * (KV_DIM / 32), 256, 0, stream>>>(v, vt, T_SEQ, KV_DIM);

    // flash attention
    flash_attn<<<1024, 256, 0, stream>>>(q, k, vt, ctx);

    // out projection (fp32 out)
    gemm_nt_128<true><<<(T_SEQ / 128) * (D_MODEL / 128), 256, 0, stream>>>(ctx, wot, out, T_SEQ, D_MODEL, D_MODEL);
}

// Round 2
// 549.307 us; speedup vs baseline: 1.5778x; 1.5778x over previous
//
#include <hip/hip_runtime.h>
#include <hip/hip_bf16.h>
#include <cstdint>
#include <cmath>

typedef __bf16 bf16;
typedef __attribute__((ext_vector_type(8))) __bf16 bf16x8;
typedef __attribute__((ext_vector_type(4))) __bf16 bf16x4;
typedef __attribute__((ext_vector_type(4))) float f32x4;

#define T_SEQ   2048
#define D_MODEL 4096
#define KV_DIM  1024
#define NH      32
#define NKV     8
#define HD      128

// async global->LDS, 16B per lane; dest = wave-uniform base + lane*16 (linear)
__device__ __forceinline__ void gload16(const void* g, void* l) {
    __builtin_amdgcn_global_load_lds(
        (__attribute__((address_space(1))) void*)g,
        (__attribute__((address_space(3))) void*)l, 16, 0, 0);
}

// ---------------- fp32 -> bf16 convert (vectorized) ----------------
__global__ void cvt_f32_bf16(const float* __restrict__ in, bf16* __restrict__ out, int n) {
    int i = (blockIdx.x * 256 + threadIdx.x) * 4;
    if (i >= n) return;
    float4 v = *(const float4*)(in + i);
    bf16x4 o = { (bf16)v.x, (bf16)v.y, (bf16)v.z, (bf16)v.w };
    *(bf16x4*)(out + i) = o;
}

// -------- fp32 [R][C] -> bf16 [C][R] transpose (LDS 32x33 tile) --------
__global__ void trans_f32_bf16(const float* __restrict__ in, bf16* __restrict__ out, int R, int C) {
    __shared__ float tile[32][33];
    int tc = C >> 5;
    int br = blockIdx.x / tc, bc = blockIdx.x % tc;
    int r0 = br << 5, c0 = bc << 5;
    int lr = threadIdx.x >> 5, lc = threadIdx.x & 31;
#pragma unroll
    for (int i = 0; i < 4; ++i)
        tile[lr + i * 8][lc] = in[(size_t)(r0 + lr + i * 8) * C + c0 + lc];
    __syncthreads();
#pragma unroll
    for (int i = 0; i < 4; ++i) {
        int oc = lr + i * 8;
        out[(size_t)(c0 + oc) * R + r0 + lc] = (bf16)tile[lc][oc];
    }
}

// -------- bf16 [R][C] -> bf16 [C][R] transpose --------
__global__ void trans_bf16(const bf16* __restrict__ in, bf16* __restrict__ out, int R, int C) {
    __shared__ bf16 tile[32][33];
    int tc = C >> 5;
    int br = blockIdx.x / tc, bc = blockIdx.x % tc;
    int r0 = br << 5, c0 = bc << 5;
    int lr = threadIdx.x >> 5, lc = threadIdx.x & 31;
#pragma unroll
    for (int i = 0; i < 4; ++i)
        tile[lr + i * 8][lc] = in[(size_t)(r0 + lr + i * 8) * C + c0 + lc];
    __syncthreads();
#pragma unroll
    for (int i = 0; i < 4; ++i) {
        int oc = lr + i * 8;
        out[(size_t)(c0 + oc) * R + r0 + lc] = tile[lc][oc];
    }
}

// ---------------- RoPE tables ----------------
__global__ void rope_table(float* __restrict__ cosT, float* __restrict__ sinT) {
    int i = blockIdx.x * 256 + threadIdx.x;  // T_SEQ*64
    if (i >= T_SEQ * 64) return;
    int t = i >> 6, j = i & 63;
    float inv = powf(10000.0f, -(float)j / 64.0f);
    float ang = (float)t * inv;
    cosT[i] = cosf(ang);
    sinT[i] = sinf(ang);
}

// ---------------- RoPE apply, in place on bf16 [T][H*128] ----------------
__global__ void rope_apply(bf16* __restrict__ qk, const float* __restrict__ cosT,
                           const float* __restrict__ sinT, int H, int stride) {
    int i = blockIdx.x * 256 + threadIdx.x;  // T*H*64
    if (i >= T_SEQ * H * 64) return;
    int j = i & 63;
    int h = (i >> 6) % H;
    int t = i / (64 * H);
    size_t base = (size_t)t * stride + h * HD;
    float a = (float)qk[base + j];
    float b = (float)qk[base + j + 64];
    float c = cosT[t * 64 + j], s = sinT[t * 64 + j];
    qk[base + j]      = (bf16)(a * c - b * s);
    qk[base + j + 64] = (bf16)(b * c + a * s);
}

// ---------------- GEMM: C[M][N] = A[M][K] * Bt[N][K]^T  (bf16, fp32 accum) ----------------
// m97 structure: 128x128 tile, BK=64, global_load_lds staging, linear LDS, 4 waves x (64x64).
// MODE 0: bf16 out to O0. MODE 1: f32 out to O0. MODE 2: qkv split (cols [0,4096) O0 stride 4096,
//         [4096,5120) O1 stride 1024, [5120,6144) O2 stride 1024), bf16.
template <int MODE>
__global__ __launch_bounds__(256, 3) void gemm_nt(const bf16* __restrict__ A,
                                                  const bf16* __restrict__ Bt,
                                                  void* __restrict__ O0, void* __restrict__ O1,
                                                  void* __restrict__ O2,
                                                  int M, int N, int K) {
    __shared__ bf16 ldsA[128 * 64];
    __shared__ bf16 ldsB[128 * 64];
    const int tiles_n = N >> 7;
    const int bm = blockIdx.x / tiles_n;
    const int bn = blockIdx.x % tiles_n;
    const int tid = threadIdx.x;
    const int lane = tid & 63;
    const int wid = tid >> 6;
    const int wr = wid >> 1, wc = wid & 1;
    const int l16 = lane & 15, l4 = lane >> 4;
    f32x4 acc[4][4] = {};
    const size_t row0 = (size_t)bm * 128, col0 = (size_t)bn * 128;
    const bf16* Abase = A + row0 * K;
    const bf16* Bbase = Bt + col0 * K;
    const int srow = wid * 8 + (lane >> 3);   // staging row within 32-row chunk
    const int scol = (lane & 7) * 8;          // staging col (elems)

    for (int k0 = 0; k0 < K; k0 += 64) {
#pragma unroll
        for (int c = 0; c < 4; ++c) {
            int r = c * 32 + srow;
            gload16(Abase + (size_t)r * K + k0 + scol, &ldsA[(c * 32 + wid * 8) * 64]);
            gload16(Bbase + (size_t)r * K + k0 + scol, &ldsB[(c * 32 + wid * 8) * 64]);
        }
        asm volatile("s_waitcnt vmcnt(0)" ::: "memory");
        __syncthreads();
#pragma unroll
        for (int kk = 0; kk < 2; ++kk) {
            bf16x8 af[4], bfr[4];
#pragma unroll
            for (int m = 0; m < 4; ++m)
                af[m] = *(const bf16x8*)&ldsA[(wr * 64 + m * 16 + l16) * 64 + kk * 32 + l4 * 8];
#pragma unroll
            for (int n = 0; n < 4; ++n)
                bfr[n] = *(const bf16x8*)&ldsB[(wc * 64 + n * 16 + l16) * 64 + kk * 32 + l4 * 8];
#pragma unroll
            for (int m = 0; m < 4; ++m)
#pragma unroll
                for (int n = 0; n < 4; ++n)
                    acc[m][n] = __builtin_amdgcn_mfma_f32_16x16x32_bf16(af[m], bfr[n], acc[m][n], 0, 0, 0);
        }
        __syncthreads();
    }
#pragma unroll
    for (int m = 0; m < 4; ++m)
#pragma unroll
        for (int n = 0; n < 4; ++n)
#pragma unroll
            for (int r = 0; r < 4; ++r) {
                size_t row = row0 + wr * 64 + m * 16 + l4 * 4 + r;
                size_t col = col0 + wc * 64 + n * 16 + l16;
                float v = acc[m][n][r];
                if (MODE == 1) {
                    ((float*)O0)[row * N + col] = v;
                } else if (MODE == 0) {
                    ((bf16*)O0)[row * N + col] = (bf16)v;
                } else {
                    if (col < 4096)
                        ((bf16*)O0)[row * 4096 + col] = (bf16)v;
                    else if (col < 5120)
                        ((bf16*)O1)[row * 1024 + (col - 4096)] = (bf16)v;
                    else
                        ((bf16*)O2)[row * 1024 + (col - 5120)] = (bf16)v;
                }
            }
}

// ---------------- causal GQA flash attention ----------------
// Block = 4 waves = 4 Q-heads of one KV-head, 16 q-rows. KVBLK=64 staged in LDS
// (global_load_lds, swizzled source + swizzled read). Online softmax per wave.
__global__ __launch_bounds__(256, 3) void flash_attn(const bf16* __restrict__ Q,
                                                     const bf16* __restrict__ Kb,
                                                     const bf16* __restrict__ Vt,
                                                     bf16* __restrict__ ctx) {
    __shared__ bf16 ldsK[64 * 128];   // [key][d], 16B granule pg = g ^ (key&15)
    __shared__ bf16 ldsV[128 * 64];   // [d][key], 16B granule pg = g ^ (d&7)
    __shared__ bf16 ldsP[4][16 * 72]; // per-wave P tile, padded stride 72
    const int tid = threadIdx.x, lane = tid & 63, wid = tid >> 6;
    const int l16 = lane & 15, l4 = lane >> 4;
    const int kvh = blockIdx.x & 7;                      // XCD-local kv-head
    const int q0 = (127 - (int)(blockIdx.x >> 3)) * 16;  // long blocks first
    const int h = kvh * 4 + wid;

    const bf16* qb = Q + (size_t)q0 * D_MODEL + h * HD;
    bf16x8 qf[4];
#pragma unroll
    for (int kk = 0; kk < 4; ++kk)
        qf[kk] = *(const bf16x8*)(qb + (size_t)l16 * D_MODEL + kk * 32 + l4 * 8);

    f32x4 acc[8] = {};
    float m_r[4], l_r[4];
#pragma unroll
    for (int r = 0; r < 4; ++r) { m_r[r] = -INFINITY; l_r[r] = 0.f; }
    const float scale = 0.08838834764831845f;  // 1/sqrt(128)
    bf16* Pw = ldsP[wid];
    const int nt = (q0 + 16 + 63) >> 6;

    const int krow = lane >> 4, kpg = lane & 15;  // K staging: 4 rows/wave-chunk
    const int vrow = lane >> 3, vpg = lane & 7;   // V staging: 8 rows/wave-chunk

    for (int t = 0; t < nt; ++t) {
        const int k0 = t * 64;
        // stage K tile [64][128]: lane writes LDS (r, pg); fetch logical granule g = pg^(r&15)
#pragma unroll
        for (int c = 0; c < 4; ++c) {
            int r = c * 16 + wid * 4 + krow;
            int g = kpg ^ (r & 15);
            gload16(Kb + (size_t)(k0 + r) * KV_DIM + kvh * HD + g * 8,
                    &ldsK[(c * 16 + wid * 4) * 128]);
        }
        // stage V^T tile [128][64]: g = pg^(r&7)
#pragma unroll
        for (int c = 0; c < 4; ++c) {
            int r = c * 32 + wid * 8 + vrow;
            int g = vpg ^ (r & 7);
            gload16(Vt + (size_t)(kvh * 128 + r) * T_SEQ + k0 + g * 8,
                    &ldsV[(c * 32 + wid * 8) * 64]);
        }
        asm volatile("s_waitcnt vmcnt(0)" ::: "memory");
        __syncthreads();

        // QK^T: s[n] = Q(16xd) * K(keys n*16+l16, d)^T
        f32x4 s[4] = {};
#pragma unroll
        for (int n = 0; n < 4; ++n) {
            int r = n * 16 + l16;
#pragma unroll
            for (int kk = 0; kk < 4; ++kk) {
                int pg = (kk * 4 + l4) ^ (r & 15);
                bf16x8 kf = *(const bf16x8*)&ldsK[r * 128 + pg * 8];
                s[n] = __builtin_amdgcn_mfma_f32_16x16x32_bf16(qf[kk], kf, s[n], 0, 0, 0);
            }
        }
        // scale + causal mask
#pragma unroll
        for (int n = 0; n < 4; ++n)
#pragma unroll
            for (int r = 0; r < 4; ++r) {
                int key = k0 + n * 16 + l16;
                int row = q0 + l4 * 4 + r;
                float sv = s[n][r] * scale;
                s[n][r] = (key > row) ? -INFINITY : sv;
            }
        // online softmax (row-reduce over l16 lanes within each l4 group)
        float f[4];
#pragma unroll
        for (int r = 0; r < 4; ++r) {
            float v = fmaxf(fmaxf(s[0][r], s[1][r]), fmaxf(s[2][r], s[3][r]));
            v = fmaxf(v, __shfl_xor(v, 1));
            v = fmaxf(v, __shfl_xor(v, 2));
            v = fmaxf(v, __shfl_xor(v, 4));
            v = fmaxf(v, __shfl_xor(v, 8));
            float mn = fmaxf(m_r[r], v);
            f[r] = __expf(m_r[r] - mn);
            m_r[r] = mn;
        }
#pragma unroll
        for (int n = 0; n < 4; ++n)
#pragma unroll
            for (int r = 0; r < 4; ++r)
                s[n][r] = __expf(s[n][r] - m_r[r]);  // exp(-inf)=0 for masked
#pragma unroll
        for (int r = 0; r < 4; ++r) {
            float ps = (s[0][r] + s[1][r]) + (s[2][r] + s[3][r]);
            ps += __shfl_xor(ps, 1);
            ps += __shfl_xor(ps, 2);
            ps += __shfl_xor(ps, 4);
            ps += __shfl_xor(ps, 8);
            l_r[r] = l_r[r] * f[r] + ps;
        }
#pragma unroll
        for (int n = 0; n < 8; ++n)
#pragma unroll
            for (int r = 0; r < 4; ++r)
                acc[n][r] *= f[r];
        // P -> LDS (bf16), per-wave region (same-wave in-order DS)
#pragma unroll
        for (int n = 0; n < 4; ++n)
#pragma unroll
            for (int r = 0; r < 4; ++r)
                Pw[(l4 * 4 + r) * 72 + n * 16 + l16] = (bf16)s[n][r];
        bf16x8 pf0 = *(const bf16x8*)&Pw[l16 * 72 + l4 * 8];
        bf16x8 pf1 = *(const bf16x8*)&Pw[l16 * 72 + 32 + l4 * 8];
        // PV: acc[n](16q x 16d) += P(16x64) * V(64 x d n*16+l16)
#pragma unroll
        for (int n = 0; n < 8; ++n) {
            int r = n * 16 + l16;
            int pg0 = l4 ^ (r & 7);
            int pg1 = (4 + l4) ^ (r & 7);
            bf16x8 v0 = *(const bf16x8*)&ldsV[r * 64 + pg0 * 8];
            bf16x8 v1 = *(const bf16x8*)&ldsV[r * 64 + pg1 * 8];
            acc[n] = __builtin_amdgcn_mfma_f32_16x16x32_bf16(pf0, v0, acc[n], 0, 0, 0);
            acc[n] = __builtin_amdgcn_mfma_f32_16x16x32_bf16(pf1, v1, acc[n], 0, 0, 0);
        }
        __syncthreads();  // protect ldsK/ldsV before next stage
    }
#pragma unroll
    for (int n = 0; n < 8; ++n)
#pragma unroll
        for (int r = 0; r < 4; ++r) {
            int row = q0 + l4 * 4 + r;
            ctx[(size_t)row * D_MODEL + h * HD + n * 16 + l16] = (bf16)(acc[n][r] / l_r[r]);
        }
}

// ---------------- host ----------------
extern "C" void kernel_launch(void* const* d_in, const int* in_sizes, int n_in,
                              void* d_out, int out_size, void* d_ws, size_t ws_size,
                              hipStream_t stream) {
    const float* x  = (const float*)d_in[0];
    const float* wq = (const float*)d_in[1];
    const float* wk = (const float*)d_in[2];
    const float* wv = (const float*)d_in[3];
    const float* wo = (const float*)d_in[4];
    float* out = (float*)d_out;

    char* ws = (char*)d_ws;
    size_t off = 0;
    auto alloc = [&](size_t bytes) {
        void* p = ws + off;
        off += (bytes + 255) & ~(size_t)255;
        return p;
    };
    bf16* xb    = (bf16*)alloc((size_t)T_SEQ * D_MODEL * 2);
    bf16* wqkvt = (bf16*)alloc((size_t)(D_MODEL + 2 * KV_DIM) * D_MODEL * 2);  // [6144][4096]
    bf16* wot   = (bf16*)alloc((size_t)D_MODEL * D_MODEL * 2);
    bf16* q     = (bf16*)alloc((size_t)T_SEQ * D_MODEL * 2);
    bf16* k     = (bf16*)alloc((size_t)T_SEQ * KV_DIM * 2);
    bf16* v     = (bf16*)alloc((size_t)T_SEQ * KV_DIM * 2);
    bf16* vt    = (bf16*)alloc((size_t)KV_DIM * T_SEQ * 2);
    bf16* ctx   = (bf16*)alloc((size_t)T_SEQ * D_MODEL * 2);
    float* cosT = (float*)alloc((size_t)T_SEQ * 64 * 4);
    float* sinT = (float*)alloc((size_t)T_SEQ * 64 * 4);

    // conversions / transposes
    cvt_f32_bf16<<<(T_SEQ * D_MODEL) / 1024, 256, 0, stream>>>(x, xb, T_SEQ * D_MODEL);
    trans_f32_bf16<<<(D_MODEL / 32) * (D_MODEL / 32), 256, 0, stream>>>(wq, wqkvt, D_MODEL, D_MODEL);
    trans_f32_bf16<<<(D_MODEL / 32) * (KV_DIM / 32), 256, 0, stream>>>(
        wk, wqkvt + (size_t)D_MODEL * D_MODEL, D_MODEL, KV_DIM);
    trans_f32_bf16<<<(D_MODEL / 32) * (KV_DIM / 32), 256, 0, stream>>>(
        wv, wqkvt + (size_t)(D_MODEL + KV_DIM) * D_MODEL, D_MODEL, KV_DIM);
    trans_f32_bf16<<<(D_MODEL / 32) * (D_MODEL / 32), 256, 0, stream>>>(wo, wot, D_MODEL, D_MODEL);
    rope_table<<<(T_SEQ * 64) / 256, 256, 0, stream>>>(cosT, sinT);

    // fused QKV projection: [2048][4096] x [6144][4096]^T
    gemm_nt<2><<<(T_SEQ / 128) * ((D_MODEL + 2 * KV_DIM) / 128), 256, 0, stream>>>(
        xb, wqkvt, q, k, v, T_SEQ, D_MODEL + 2 * KV_DIM, D_MODEL);

    // RoPE
    rope_apply<<<(T_SEQ * NH * 64) / 256, 256, 0, stream>>>(q, cosT, sinT, NH, D_MODEL);
    rope_apply<<<(T_SEQ * NKV * 64) / 256, 256, 0, stream>>>(k, cosT, sinT, NKV, KV_DIM);

    // V^T per kv-head: [2048][1024] -> [1024][2048]
    trans_bf16<<<(T_SEQ / 32) * (KV_DIM / 32), 256, 0, stream>>>(v, vt, T_SEQ, KV_DIM);

    // flash attention: 8 kv-heads x 128 q-chunks
    flash_attn<<<1024, 256, 0, stream>>>(q, k, vt, ctx);

    // out projection (fp32 out)
    gemm_nt<1><<<(T_SEQ / 128) * (D_MODEL / 128), 256, 0, stream>>>(
        ctx, wot, out, nullptr, nullptr, T_SEQ, D_MODEL, D_MODEL);
}